// Round 11
// baseline (387.304 us; speedup 1.0000x reference)
//
#include <hip/hip_runtime.h>
#include <hip/hip_bf16.h>
#include <math.h>

#define DF 64
#define NPB 128        // nodes per bucket (shift 7)
#define EPB 2048       // edges per block in bucket phases
#define DCAP 4608      // Phase-D per-bucket edge capacity

typedef __attribute__((ext_vector_type(8))) short short8v;   // 8 bf16 = 4 VGPRs
typedef __attribute__((ext_vector_type(4))) float f32x4;

__global__ __launch_bounds__(256) void zero_int_kernel(int* __restrict__ p, int n) {
  int i = blockIdx.x * 256 + threadIdx.x;
  if (i < n) p[i] = 0;
}

// Phase A: per-block LDS histogram of dst buckets -> global bucket counts
__global__ __launch_bounds__(256) void bkt_count_kernel(const int* __restrict__ dst,
                                                        int* __restrict__ bcount,
                                                        int e, int nbk) {
  __shared__ int cnt[512];
  for (int i = threadIdx.x; i < nbk; i += 256) cnt[i] = 0;
  __syncthreads();
  const int eb = blockIdx.x * EPB;
  const int ee = (eb + EPB < e) ? (eb + EPB) : e;
  for (int i = eb + threadIdx.x; i < ee; i += 256) atomicAdd(&cnt[dst[i] >> 7], 1);
  __syncthreads();
  for (int i = threadIdx.x; i < nbk; i += 256)
    if (cnt[i]) atomicAdd(&bcount[i], cnt[i]);
}

// Phase B: one-block exclusive scan of bucket counts (nbk <= 512); init cursors
__global__ __launch_bounds__(512) void bkt_scan_kernel(const int* __restrict__ bcount,
                                                       int* __restrict__ boff,
                                                       int* __restrict__ bcur,
                                                       int* __restrict__ rowp_last,
                                                       int e, int nbk) {
  __shared__ int a[512];
  const int t = threadIdx.x;
  int v = (t < nbk) ? bcount[t] : 0;
  a[t] = v;
  __syncthreads();
  for (int off = 1; off < 512; off <<= 1) {
    int add = (t >= off) ? a[t - off] : 0;
    __syncthreads();
    a[t] += add;
    __syncthreads();
  }
  int excl = a[t] - v;
  if (t < nbk) { boff[t] = excl; bcur[t] = excl; }
  if (t == nbk - 1) { boff[nbk] = excl + v; rowp_last[0] = e; }
}

// Phase C: bin edges into bucket segments as (src, dst&127) pairs.
__global__ __launch_bounds__(256) void bkt_fill_kernel(const int* __restrict__ src,
                                                       const int* __restrict__ dst,
                                                       int* __restrict__ bcur,
                                                       int2* __restrict__ bpairs,
                                                       int e, int nbk) {
  __shared__ int cnt[512];
  __shared__ int base[512];
  for (int i = threadIdx.x; i < nbk; i += 256) cnt[i] = 0;
  __syncthreads();
  const int eb = blockIdx.x * EPB;
  int s[8], d[8], r[8];
#pragma unroll
  for (int q = 0; q < 8; ++q) {
    int i = eb + q * 256 + threadIdx.x;
    bool ok = i < e;
    s[q] = ok ? src[i] : 0;
    d[q] = ok ? dst[i] : 0;
    r[q] = ok ? atomicAdd(&cnt[d[q] >> 7], 1) : 0;
  }
  __syncthreads();
  for (int i = threadIdx.x; i < nbk; i += 256)
    base[i] = cnt[i] ? atomicAdd(&bcur[i], cnt[i]) : 0;
  __syncthreads();
#pragma unroll
  for (int q = 0; q < 8; ++q) {
    int i = eb + q * 256 + threadIdx.x;
    if (i < e) {
      int b = d[q] >> 7;
      bpairs[base[b] + r[q]] = make_int2(s[q], d[q] & (NPB - 1));
    }
  }
}

// Phase D: one workgroup per bucket. Local hist -> scan -> LDS scatter.
__global__ __launch_bounds__(256) void bkt_csr_kernel(const int2* __restrict__ bpairs,
                                                      const int* __restrict__ boff,
                                                      int* __restrict__ rowp,
                                                      int* __restrict__ csr,
                                                      int n, int nbk) {
  __shared__ int cnt[NPB], cur[NPB], sa[NPB];
  __shared__ int lsrc[DCAP], ldst[DCAP], lcsr[DCAP];
  const int b = blockIdx.x;
  const int t = threadIdx.x;
  const int e0 = boff[b];
  int cnt_e = boff[b + 1] - e0;
  if (cnt_e > DCAP) cnt_e = DCAP;
  if (t < NPB) cnt[t] = 0;
  __syncthreads();
  for (int i = t; i < cnt_e; i += 256) {
    int2 p = bpairs[e0 + i];
    lsrc[i] = p.x;
    ldst[i] = p.y;
    atomicAdd(&cnt[p.y], 1);
  }
  __syncthreads();
  if (t < NPB) sa[t] = cnt[t];
  __syncthreads();
  for (int off = 1; off < NPB; off <<= 1) {
    int add = (t < NPB && t >= off) ? sa[t - off] : 0;
    __syncthreads();
    if (t < NPB) sa[t] += add;
    __syncthreads();
  }
  if (t < NPB) {
    int excl = sa[t] - cnt[t];
    cur[t] = excl;
    int node = b * NPB + t;
    if (node < n) rowp[node] = e0 + excl;
  }
  __syncthreads();
  for (int i = t; i < cnt_e; i += 256) {
    int p = atomicAdd(&cur[ldst[i]], 1);
    lcsr[p] = lsrc[i];
  }
  __syncthreads();
  for (int i = t; i < cnt_e; i += 256) csr[e0 + i] = lcsr[i];
}

// Combined GEMM weights, bf16, layout WB[l][c][k], c in 0..255, k in 0..127.
// K mapping: k<32 segA, 32..63 segB, 64..95 hA, 96..127 hB (== old [seg|h] order).
__global__ __launch_bounds__(256) void wb_kernel(const float* __restrict__ W,
                                                 const float* __restrict__ wih,
                                                 const float* __restrict__ whh,
                                                 __hip_bfloat16* __restrict__ WB,
                                                 int total) {
  int idx = blockIdx.x * 256 + threadIdx.x;
  if (idx >= total) return;
  int k = idx & 127;
  int c = (idx >> 7) & 255;
  int l = idx >> 15;
  int g = c >> 6;   // 0:r 1:z 2:i_n 3:h_n
  int f = c & 63;
  float v = 0.f;
  if (k < 64) {
    if (g != 3) {
      int crow = (g == 0) ? f : (g == 1) ? (64 + f) : (128 + f);
      const float* wr = W + ((size_t)l * 64 + k) * 64;
      const float* ir = wih + (size_t)crow * 64;
      float s = 0.f;
#pragma unroll
      for (int t2 = 0; t2 < 64; ++t2) s = fmaf(wr[t2], ir[t2], s);
      v = s;
    }
  } else {
    if (g != 2) {
      int crow = (g == 0) ? f : (g == 1) ? (64 + f) : (128 + f);
      v = whh[(size_t)crow * 64 + (k - 64)];
    }
  }
  WB[idx] = __float2bfloat16(v);
}

// split fp32 x -> bf16 feature-half arrays hA (f 0..31), hB (f 32..63)
__global__ __launch_bounds__(256) void cvt_kernel(const float* __restrict__ x,
                                                  __hip_bfloat16* __restrict__ hA,
                                                  __hip_bfloat16* __restrict__ hB, int n) {
  int i = blockIdx.x * 256 + threadIdx.x;
  if (i >= n) return;
  int f = i & 63, node = i >> 6;
  __hip_bfloat16 v = __float2bfloat16(x[i]);
  if (f < 32) hA[(size_t)node * 32 + f] = v;
  else        hB[(size_t)node * 32 + (f - 32)] = v;
}

// Half-feature gather: one wave per node over a 3.2MB array (fits per-XCD L2).
// lane = g*8+fl: 8 edge sub-streams x 8 lanes x 8B -> 8 edge-rows (512B) per
// wave instruction (same issue efficiency as the unified R10 gather).
__global__ __launch_bounds__(256) void gather_half_kernel(
    const __hip_bfloat16* __restrict__ hX, const int* __restrict__ rowp,
    const int* __restrict__ csr, __hip_bfloat16* __restrict__ segX, int n) {
  int w = (int)((blockIdx.x * 256 + threadIdx.x) >> 6);
  if (w >= n) return;
  const int lane = threadIdx.x & 63;
  const int g = lane >> 3;       // edge sub-stream 0..7
  const int fl = lane & 7;       // feature quad: features fl*4..fl*4+3
  const int beg = rowp[w], end = rowp[w + 1];
  float a0 = 0.f, a1 = 0.f, a2 = 0.f, a3 = 0.f;
  int e = beg + g;
  for (; e + 8 < end; e += 16) {
    int s0 = csr[e], s1 = csr[e + 8];
    uint2 v0 = *(const uint2*)(hX + (size_t)s0 * 32 + fl * 4);
    uint2 v1 = *(const uint2*)(hX + (size_t)s1 * 32 + fl * 4);
    a0 += __uint_as_float(v0.x << 16);
    a1 += __uint_as_float(v0.x & 0xffff0000u);
    a2 += __uint_as_float(v0.y << 16);
    a3 += __uint_as_float(v0.y & 0xffff0000u);
    a0 += __uint_as_float(v1.x << 16);
    a1 += __uint_as_float(v1.x & 0xffff0000u);
    a2 += __uint_as_float(v1.y << 16);
    a3 += __uint_as_float(v1.y & 0xffff0000u);
  }
  if (e < end) {
    int s0 = csr[e];
    uint2 v0 = *(const uint2*)(hX + (size_t)s0 * 32 + fl * 4);
    a0 += __uint_as_float(v0.x << 16);
    a1 += __uint_as_float(v0.x & 0xffff0000u);
    a2 += __uint_as_float(v0.y << 16);
    a3 += __uint_as_float(v0.y & 0xffff0000u);
  }
  // combine the 8 edge sub-streams (lanes differing in bits 3-5)
  a0 += __shfl_xor(a0, 8);  a1 += __shfl_xor(a1, 8);
  a2 += __shfl_xor(a2, 8);  a3 += __shfl_xor(a3, 8);
  a0 += __shfl_xor(a0, 16); a1 += __shfl_xor(a1, 16);
  a2 += __shfl_xor(a2, 16); a3 += __shfl_xor(a3, 16);
  a0 += __shfl_xor(a0, 32); a1 += __shfl_xor(a1, 32);
  a2 += __shfl_xor(a2, 32); a3 += __shfl_xor(a3, 32);
  if (g == 0) {
    ushort2 p0 = make_ushort2(__bfloat16_as_ushort(__float2bfloat16(a0)),
                              __bfloat16_as_ushort(__float2bfloat16(a1)));
    ushort2 p1 = make_ushort2(__bfloat16_as_ushort(__float2bfloat16(a2)),
                              __bfloat16_as_ushort(__float2bfloat16(a3)));
    uint2 packed = make_uint2(((uint)p0.y << 16) | p0.x, ((uint)p1.y << 16) | p1.x);
    *(uint2*)(segX + (size_t)w * 32 + fl * 4) = packed;
  }
}

// swizzled LDS B-fragment read
__device__ __forceinline__ short8v ldB(const char* sB, int c, int chunk) {
  return *(const short8v*)(sB + c * 256 + ((chunk ^ (c & 15)) * 16));
}

#define MFMA(acc, a, b) acc = __builtin_amdgcn_mfma_f32_16x16x32_bf16(a, b, acc, 0, 0, 0)

// Fused GRU step via MFMA, split bf16 h state (hA/hB read + written in place).
__global__ __launch_bounds__(256, 2) void gru_mfma_kernel(
    const __hip_bfloat16* __restrict__ segA, const __hip_bfloat16* __restrict__ segB,
    __hip_bfloat16* __restrict__ hA, __hip_bfloat16* __restrict__ hB,
    const float* __restrict__ bih, const float* __restrict__ bhh,
    const __hip_bfloat16* __restrict__ WB, float* __restrict__ out,
    int writeOut, int n) {
  __shared__ __hip_bfloat16 sB[256 * 128];  // 64 KiB, chunk-XOR swizzled
#pragma unroll
  for (int i = 0; i < 16; ++i) {
    int idx = i * 256 + threadIdx.x;
    int c = idx >> 4, ch = idx & 15;
    short8v v = *(const short8v*)(WB + (size_t)c * 128 + ch * 8);
    *(short8v*)((char*)sB + c * 256 + ((ch ^ (c & 15)) * 16)) = v;
  }
  __syncthreads();

  const char* sBc = (const char*)sB;
  const int lane = threadIdx.x & 63;
  const int wid = threadIdx.x >> 6;
  const int row = lane & 15;
  const int quad = lane >> 4;
  const int ch0 = quad, ch1 = 4 + quad, ch2 = 8 + quad, ch3 = 12 + quad;

  float bi_r[4], bi_z[4], bi_n[4], bh_r[4], bh_z[4], bh_n[4];
#pragma unroll
  for (int j = 0; j < 4; ++j) {
    int f = j * 16 + row;
    bi_r[j] = bih[f]; bi_z[j] = bih[64 + f]; bi_n[j] = bih[128 + f];
    bh_r[j] = bhh[f]; bh_z[j] = bhh[64 + f]; bh_n[j] = bhh[128 + f];
  }

  for (int nb0 = blockIdx.x * 64; nb0 < n; nb0 += gridDim.x * 64) {
    const int nb = nb0 + wid * 16;
    if (nb >= n) continue;
    const size_t ro = (size_t)(nb + row) * 32 + quad * 8;
    const short8v a0 = *(const short8v*)(segA + ro);  // k  0..31
    const short8v a1 = *(const short8v*)(segB + ro);  // k 32..63
    const short8v a2 = *(const short8v*)(hA + ro);    // k 64..95
    const short8v a3 = *(const short8v*)(hB + ro);    // k 96..127

    f32x4 accR[4], accZ[4], accN[4], accH[4];
#pragma unroll
    for (int j = 0; j < 4; ++j) {
      accR[j] = (f32x4){0.f, 0.f, 0.f, 0.f};
      accZ[j] = (f32x4){0.f, 0.f, 0.f, 0.f};
      accN[j] = (f32x4){0.f, 0.f, 0.f, 0.f};
      accH[j] = (f32x4){0.f, 0.f, 0.f, 0.f};
    }
#pragma unroll
    for (int j = 0; j < 4; ++j) {
      MFMA(accR[j], a0, ldB(sBc, j * 16 + row, ch0));
      MFMA(accR[j], a1, ldB(sBc, j * 16 + row, ch1));
      MFMA(accR[j], a2, ldB(sBc, j * 16 + row, ch2));
      MFMA(accR[j], a3, ldB(sBc, j * 16 + row, ch3));
      MFMA(accZ[j], a0, ldB(sBc, 64 + j * 16 + row, ch0));
      MFMA(accZ[j], a1, ldB(sBc, 64 + j * 16 + row, ch1));
      MFMA(accZ[j], a2, ldB(sBc, 64 + j * 16 + row, ch2));
      MFMA(accZ[j], a3, ldB(sBc, 64 + j * 16 + row, ch3));
      MFMA(accN[j], a0, ldB(sBc, 128 + j * 16 + row, ch0));
      MFMA(accN[j], a1, ldB(sBc, 128 + j * 16 + row, ch1));
      MFMA(accH[j], a2, ldB(sBc, 192 + j * 16 + row, ch2));
      MFMA(accH[j], a3, ldB(sBc, 192 + j * 16 + row, ch3));
    }
#pragma unroll
    for (int j = 0; j < 4; ++j) {
      __hip_bfloat16* hX = (j < 2) ? hA : hB;
      const int fo = ((j & 1) << 4) + row;
#pragma unroll
      for (int e = 0; e < 4; ++e) {
        const int node = nb + quad * 4 + e;
        const int f = j * 16 + row;
        const float hprev = __bfloat162float(hX[(size_t)node * 32 + fo]);
        const float r = 1.f / (1.f + __expf(-(accR[j][e] + bi_r[j] + bh_r[j])));
        const float z = 1.f / (1.f + __expf(-(accZ[j][e] + bi_z[j] + bh_z[j])));
        const float nn = tanhf(accN[j][e] + bi_n[j] + r * (accH[j][e] + bh_n[j]));
        const float ho = fmaf(z, hprev - nn, nn);
        hX[(size_t)node * 32 + fo] = __float2bfloat16(ho);
        if (writeOut) out[(size_t)node * DF + f] = ho;
      }
    }
  }
}

extern "C" void kernel_launch(void* const* d_in, const int* in_sizes, int n_in,
                              void* d_out, int out_size, void* d_ws, size_t ws_size,
                              hipStream_t stream) {
  const float* x   = (const float*)d_in[0];
  const int*   ei  = (const int*)d_in[1];
  const float* wgt = (const float*)d_in[2];
  const float* wih = (const float*)d_in[3];
  const float* whh = (const float*)d_in[4];
  const float* bih = (const float*)d_in[5];
  const float* bhh = (const float*)d_in[6];
  float* out = (float*)d_out;

  const int N = in_sizes[0] / DF;
  const int E = in_sizes[1] / 2;
  const int L = in_sizes[2] / (DF * DF);

  const int* srcv = ei;
  const int* dstv = ei + E;

  __hip_bfloat16* hA   = (__hip_bfloat16*)d_ws;
  __hip_bfloat16* hB   = hA + (size_t)N * 32;
  __hip_bfloat16* segA = hB + (size_t)N * 32;
  __hip_bfloat16* segB = segA + (size_t)N * 32;
  __hip_bfloat16* WB   = segB + (size_t)N * 32;
  int* rowp   = (int*)(WB + (size_t)L * 256 * 128);
  int* csr    = rowp + (N + 1);
  int* bcount = csr + E;
  int* boff   = bcount + 512;
  int* bcur   = boff + 513;
  int2* bpairs = (int2*)(bcur + 512);

  const int NBK = (N + NPB - 1) >> 7;      // 391 (must be <= 512)
  const int EB  = (E + EPB - 1) / EPB;     // 391

  // CSR build via bucket counting-sort
  zero_int_kernel<<<(NBK + 255) / 256, 256, 0, stream>>>(bcount, NBK);
  bkt_count_kernel<<<EB, 256, 0, stream>>>(dstv, bcount, E, NBK);
  bkt_scan_kernel<<<1, 512, 0, stream>>>(bcount, boff, bcur, rowp + N, E, NBK);
  bkt_fill_kernel<<<EB, 256, 0, stream>>>(srcv, dstv, bcur, bpairs, E, NBK);
  bkt_csr_kernel<<<NBK, 256, 0, stream>>>(bpairs, boff, rowp, csr, N, NBK);

  // combined bf16 GEMM weights + split bf16 copy of initial h
  wb_kernel<<<(L * 256 * 128 + 255) / 256, 256, 0, stream>>>(wgt, wih, whh, WB,
                                                             L * 256 * 128);
  cvt_kernel<<<(N * DF + 255) / 256, 256, 0, stream>>>(x, hA, hB, N * DF);

  const int gatherGrid = (N * DF + 255) / 256;  // one wave per node
  const int gruGrid = (N + 63) / 64;
  for (int i = 0; i < L; ++i) {
    gather_half_kernel<<<gatherGrid, 256, 0, stream>>>(hA, rowp, csr, segA, N);
    gather_half_kernel<<<gatherGrid, 256, 0, stream>>>(hB, rowp, csr, segB, N);
    gru_mfma_kernel<<<gruGrid, 256, 0, stream>>>(segA, segB, hA, hB, bih, bhh,
                                                 WB + (size_t)i * 256 * 128, out,
                                                 (i == L - 1) ? 1 : 0, N);
  }
}